// Round 1
// baseline (360.203 us; speedup 1.0000x reference)
//
#include <hip/hip_runtime.h>

// DiffeomorphicTransform R11: 2x2x2 cube-blocked float4 intermediate layout.
//
// Theory: late steps are bound by divergent-gather LINE traffic: +-25-voxel white
// scatter makes each per-voxel corner-pair load pull its own ~128B L2/L3 line
// (~4.7 lines/voxel = ~600B fill for 96B useful). Blocking the volume into
// 2x2x2-voxel cubes of float4 (8*16B = ONE aligned 128B line) colocates the whole
// trilinear corner neighborhood: expected distinct lines/voxel = (3/2)^3 = 3.375
// (-28%), and the remaining corner loads become guaranteed L1 hits.
// Also: repack dispatch eliminated — step 1 reads planar velocity directly
// (scale 2^-7 is an exact pow2, folded into loads; bit-identical arithmetic).
// Keeps z-slab XCD swizzle (R6) + analytic identity grid (R3).
// ws layout: bufA @ 0, bufB @ 48MB; each N*16B = 40MB; ws_size = 256MB (memset evidence).

constexpr int D = 128, H = 160, W = 128;
constexpr int N = D * H * W;                 // 2,621,440 voxels
constexpr int HC = H / 2, WC = W / 2;        // 80, 64
constexpr int NBLK = (D / 2) * (H / 2) * (W / 64);   // 64*80*2 = 10240 blocks
constexpr int NUM_XCD = 8;
constexpr int CHUNKS_PER_XCD = NBLK / NUM_XCD;       // 1280

struct alignas(4) f2 { float a, b; };  // 4B-aligned pair load (R10 proved dwordx3@4B ok)

__device__ __forceinline__ int cube_idx(int z, int y, int x) {
    // [z/2][y/2][x/2] cube of 8 voxels; slot = (z&1,y&1,x&1). One cube = 128B line.
    return ((((z >> 1) * HC + (y >> 1)) * WC + (x >> 1)) << 3)
         | ((z & 1) << 2) | ((y & 1) << 1) | (x & 1);
}

template <bool SRC_PLANAR, bool DST_PLANAR>
__global__ __launch_bounds__(256)
void diffeo_step(const void* __restrict__ src_raw,
                 const float* __restrict__ rf_p,
                 void* __restrict__ dst_raw)
{
    // z-slab XCD swizzle (R6-validated): contiguous 16-slice slab per XCD
    const int b   = blockIdx.x;
    const int xcd = b & (NUM_XCD - 1);
    const int k   = b >> 3;
    const int vb  = xcd * CHUNKS_PER_XCD + k;

    // brick decomposition: block covers z-pair x y-pair x 64 consecutive x
    // -> block owns 32 complete cubes (4KB), streaming reads/writes full lines.
    const int zc  = vb / (HC * 2);
    const int rem = vb - zc * (HC * 2);
    const int yc  = rem >> 1;
    const int xh  = rem & 1;

    const int t = threadIdx.x;
    const int x = (xh << 6) | (t & 63);
    const int y = (yc << 1) | ((t >> 6) & 1);
    const int z = (zc << 1) | (t >> 7);

    const float rf = rf_p[0];
    const float s  = 1.0f / 128.0f;          // 2^-7, exact

    float3 f;
    if (SRC_PLANAR) {
        const float* sp = (const float*)src_raw;
        const int i = (z * H + y) * W + x;
        f = make_float3(sp[i] * s, sp[i + N] * s, sp[i + 2 * N] * s);
    } else {
        const float4 v = ((const float4*)src_raw)[cube_idx(z, y, x)];
        f = make_float3(v.x, v.y, v.z);
    }

    // analytic identity grid: unnormalized coord = x + flow*rf*0.5*(dim-1)
    const float ix = fminf(fmaxf((float)x + f.x * (rf * 0.5f * (float)(W - 1)), 0.0f), (float)(W - 1));
    const float iy = fminf(fmaxf((float)y + f.y * (rf * 0.5f * (float)(H - 1)), 0.0f), (float)(H - 1));
    const float iz = fminf(fmaxf((float)z + f.z * (rf * 0.5f * (float)(D - 1)), 0.0f), (float)(D - 1));

    const float x0f = floorf(ix), y0f = floorf(iy), z0f = floorf(iz);
    const float wx = ix - x0f, wy = iy - y0f, wz = iz - z0f;
    const int x0 = (int)x0f, y0 = (int)y0f, z0 = (int)z0f;
    const int y1 = min(y0 + 1, H - 1);
    const int z1 = min(z0 + 1, D - 1);

    // rows q: (z0,y0),(z0,y1),(z1,y0),(z1,y1) -> weights w00,w01,w10,w11 (R10 order)
    float3 p0[4], p1[4];

    if (SRC_PLANAR) {
        // planar velocity gathers (step 1: displacement ~<1 voxel, lines shared)
        const float* sp = (const float*)src_raw;
        const int xb = min(x0, W - 2);
        const bool hix = (x0 == W - 1);       // then wx==0, p1 unused-weight
        int ofs[4];
        ofs[0] = (z0 * H + y0) * W + xb;
        ofs[1] = (z0 * H + y1) * W + xb;
        ofs[2] = (z1 * H + y0) * W + xb;
        ofs[3] = (z1 * H + y1) * W + xb;
#pragma unroll
        for (int q = 0; q < 4; ++q) {
            const f2 px = *(const f2*)(sp + ofs[q]);
            const f2 py = *(const f2*)(sp + N + ofs[q]);
            const f2 pz = *(const f2*)(sp + 2 * N + ofs[q]);
            p0[q] = make_float3(px.a * s, py.a * s, pz.a * s);
            p1[q] = make_float3(px.b * s, py.b * s, pz.b * s);
        }
        if (hix) {
#pragma unroll
            for (int q = 0; q < 4; ++q) p0[q] = p1[q];   // wx==0 here, exact
        }
    } else {
        // cube-blocked gathers: 8 float4 loads; corners sharing a cube line are L1 hits
        const float4* sc = (const float4*)src_raw;
        const int x1 = min(x0 + 1, W - 1);
#pragma unroll
        for (int q = 0; q < 4; ++q) {
            const int zi = (q & 2) ? z1 : z0;
            const int yi = (q & 1) ? y1 : y0;
            const float4 a  = sc[cube_idx(zi, yi, x0)];
            const float4 bq = sc[cube_idx(zi, yi, x1)];
            p0[q] = make_float3(a.x, a.y, a.z);
            p1[q] = make_float3(bq.x, bq.y, bq.z);
        }
    }

    const float omx = 1.0f - wx, omy = 1.0f - wy, omz = 1.0f - wz;
    const float w00 = omz * omy, w01 = omz * wy, w10 = wz * omy, w11 = wz * wy;

    // bilinear over (z,y) of the x-lerped corner values, per channel (R10 association)
    const float vx = w00 * (omx * p0[0].x + wx * p1[0].x)
                   + w01 * (omx * p0[1].x + wx * p1[1].x)
                   + w10 * (omx * p0[2].x + wx * p1[2].x)
                   + w11 * (omx * p0[3].x + wx * p1[3].x);
    const float vy = w00 * (omx * p0[0].y + wx * p1[0].y)
                   + w01 * (omx * p0[1].y + wx * p1[1].y)
                   + w10 * (omx * p0[2].y + wx * p1[2].y)
                   + w11 * (omx * p0[3].y + wx * p1[3].y);
    const float vz = w00 * (omx * p0[0].z + wx * p1[0].z)
                   + w01 * (omx * p0[1].z + wx * p1[1].z)
                   + w10 * (omx * p0[2].z + wx * p1[2].z)
                   + w11 * (omx * p0[3].z + wx * p1[3].z);

    const float o0 = f.x + vx, o1 = f.y + vy, o2 = f.z + vz;

    if (DST_PLANAR) {
        float* __restrict__ dp = (float*)dst_raw;
        const int i = (z * H + y) * W + x;
        dp[i] = o0; dp[i + N] = o1; dp[i + 2 * N] = o2;
    } else {
        ((float4*)dst_raw)[cube_idx(z, y, x)] = make_float4(o0, o1, o2, 0.0f);
    }
}

extern "C" void kernel_launch(void* const* d_in, const int* in_sizes, int n_in,
                              void* d_out, int out_size, void* d_ws, size_t ws_size,
                              hipStream_t stream)
{
    const float* vel = (const float*)d_in[0];   // [1,3,128,160,128] planar
    const float* rf  = (const float*)d_in[2];   // scalar range_flow

    float4* A = (float4*)d_ws;
    float4* B = (float4*)((char*)d_ws + (size_t)48 * 1024 * 1024);

    const dim3 blk(256);
    const dim3 grd(NBLK);                       // 10240 blocks

    // 7 dispatches, no repack: s1 reads planar velocity (x 2^-7 folded, exact)
    diffeo_step<true , false><<<grd, blk, 0, stream>>>(vel, rf, A);       // s1
    diffeo_step<false, false><<<grd, blk, 0, stream>>>(A,   rf, B);       // s2
    diffeo_step<false, false><<<grd, blk, 0, stream>>>(B,   rf, A);       // s3
    diffeo_step<false, false><<<grd, blk, 0, stream>>>(A,   rf, B);       // s4
    diffeo_step<false, false><<<grd, blk, 0, stream>>>(B,   rf, A);       // s5
    diffeo_step<false, false><<<grd, blk, 0, stream>>>(A,   rf, B);       // s6
    diffeo_step<false, true ><<<grd, blk, 0, stream>>>(B,   rf, d_out);   // s7
}

// Round 2
// 301.417 us; speedup vs baseline: 1.1950x; 1.1950x over previous
//
#include <hip/hip_runtime.h>

// DiffeomorphicTransform R12: R10's channel-interleaved float3 layout (proven
// 296.5us) + repack-dispatch elimination + nontemporal final store.
//
// R11 post-mortem: 2x2x2 cube-float4 layout regressed every step to a uniform
// ~49us (vs <=40 in R10) -- per-step uniformity across scatter magnitudes rules
// out line-fanout as the bottleneck; the 49/37 ratio matches the vmem
// bytes-per-thread ratio (160 vs 120 B) and the cube layout halved inter-lane
// x-coalescing (16B stride, 2 lanes/line vs ~10.7 at 12B). The binding resource
// is the per-CU vmem request path; dense 12B interleave is strictly better at
// every step. R10 structure restored exactly (same FMA association -> same
// absmax 0.015625).
//
// R12 deltas vs R10:
//  - step 1 reads planar velocity directly, folding the exact 2^-7 scale into
//    the loads (bit-identical; R11 validated) -> repack dispatch eliminated.
//  - final planar store uses __builtin_nontemporal_store (output never re-read;
//    avoids evicting step-7 gather lines from L2).
// Keeps z-slab XCD swizzle (R6) + analytic identity grid (R3).

constexpr int D = 128, H = 160, W = 128;
constexpr int N = D * H * W;             // 2,621,440 voxels
constexpr int VOX_BLOCKS = N / 256;      // 10240 blocks
constexpr int NUM_XCD = 8;
constexpr int CHUNKS_PER_XCD = VOX_BLOCKS / NUM_XCD;   // 1280

struct alignas(4) f2 { float a, b; };    // 4B-aligned pair load

template <bool SRC_PLANAR, bool DST_PLANAR>
__global__ __launch_bounds__(256)
void diffeo_step(const void* __restrict__ src_raw,
                 const float* __restrict__ rf_p,
                 void* __restrict__ dst_raw)
{
    // z-slab XCD swizzle (R6-validated)
    const int b   = blockIdx.x;              // 0..10239
    const int xcd = b & (NUM_XCD - 1);
    const int k   = b >> 3;                  // 0..1279
    const int vb  = xcd * CHUNKS_PER_XCD + k;
    const int i   = vb * 256 + threadIdx.x;  // voxel id [0,N)

    const float rf = rf_p[0];
    const float s  = 1.0f / 128.0f;          // 2^-7, exact

    // voxel coords (W=128 pow2)
    const int x = i & (W - 1);
    const int r = i >> 7;                    // z*H + y
    const int y = r % H;
    const int z = r / H;

    float3 f;
    if (SRC_PLANAR) {
        const float* sp = (const float*)src_raw;
        f = make_float3(sp[i] * s, sp[i + N] * s, sp[i + 2 * N] * s);
    } else {
        f = ((const float3*)src_raw)[i];
    }

    // analytic identity grid: unnormalized coord = x + flow*rf*0.5*(dim-1)
    const float ix = fminf(fmaxf((float)x + f.x * (rf * 0.5f * (float)(W - 1)), 0.0f), (float)(W - 1));
    const float iy = fminf(fmaxf((float)y + f.y * (rf * 0.5f * (float)(H - 1)), 0.0f), (float)(H - 1));
    const float iz = fminf(fmaxf((float)z + f.z * (rf * 0.5f * (float)(D - 1)), 0.0f), (float)(D - 1));

    const float x0f = floorf(ix), y0f = floorf(iy), z0f = floorf(iz);
    const float wx = ix - x0f, wy = iy - y0f, wz = iz - z0f;
    const int x0 = (int)x0f, y0 = (int)y0f, z0 = (int)z0f;
    const int y1 = min(y0 + 1, H - 1);
    const int z1 = min(z0 + 1, D - 1);

    // corner-pair base: x0==W-1 implies wx==0 (x1==x0) -> select hi triplet.
    const int xb = min(x0, W - 2);
    const bool hix = (x0 == W - 1);

    int ofs[4];
    ofs[0] = (z0 * H + y0) * W + xb;
    ofs[1] = (z0 * H + y1) * W + xb;
    ofs[2] = (z1 * H + y0) * W + xb;
    ofs[3] = (z1 * H + y1) * W + xb;

    // 8 gathers: per row-corner, two adjacent triplets (24 contiguous bytes
    // covering x0 and x1 for ALL 3 channels)
    float3 p0[4], p1[4];
    if (SRC_PLANAR) {
        const float* sp = (const float*)src_raw;
#pragma unroll
        for (int q = 0; q < 4; ++q) {
            const f2 px = *(const f2*)(sp + ofs[q]);
            const f2 py = *(const f2*)(sp + N + ofs[q]);
            const f2 pz = *(const f2*)(sp + 2 * N + ofs[q]);
            p0[q] = make_float3(px.a * s, py.a * s, pz.a * s);
            p1[q] = make_float3(px.b * s, py.b * s, pz.b * s);
        }
    } else {
        const float3* s3 = (const float3*)src_raw;
#pragma unroll
        for (int q = 0; q < 4; ++q) {
            p0[q] = s3[ofs[q]];
            p1[q] = s3[ofs[q] + 1];
        }
    }
    if (hix) {
#pragma unroll
        for (int q = 0; q < 4; ++q) p0[q] = p1[q];   // wx==0 here, exact
    }

    const float omx = 1.0f - wx, omy = 1.0f - wy, omz = 1.0f - wz;
    const float w00 = omz * omy, w01 = omz * wy, w10 = wz * omy, w11 = wz * wy;

    // bilinear over (z,y) of the x-lerped corner values, per channel
    const float vx = w00 * (omx * p0[0].x + wx * p1[0].x)
                   + w01 * (omx * p0[1].x + wx * p1[1].x)
                   + w10 * (omx * p0[2].x + wx * p1[2].x)
                   + w11 * (omx * p0[3].x + wx * p1[3].x);
    const float vy = w00 * (omx * p0[0].y + wx * p1[0].y)
                   + w01 * (omx * p0[1].y + wx * p1[1].y)
                   + w10 * (omx * p0[2].y + wx * p1[2].y)
                   + w11 * (omx * p0[3].y + wx * p1[3].y);
    const float vz = w00 * (omx * p0[0].z + wx * p1[0].z)
                   + w01 * (omx * p0[1].z + wx * p1[1].z)
                   + w10 * (omx * p0[2].z + wx * p1[2].z)
                   + w11 * (omx * p0[3].z + wx * p1[3].z);

    const float o0 = f.x + vx, o1 = f.y + vy, o2 = f.z + vz;

    if (DST_PLANAR) {
        float* __restrict__ dp = (float*)dst_raw;
        __builtin_nontemporal_store(o0, dp + i);
        __builtin_nontemporal_store(o1, dp + i + N);
        __builtin_nontemporal_store(o2, dp + i + 2 * N);
    } else {
        ((float3*)dst_raw)[i] = make_float3(o0, o1, o2);
    }
}

extern "C" void kernel_launch(void* const* d_in, const int* in_sizes, int n_in,
                              void* d_out, int out_size, void* d_ws, size_t ws_size,
                              hipStream_t stream)
{
    const float* vel = (const float*)d_in[0];   // [1,3,128,160,128] planar
    const float* rf  = (const float*)d_in[2];   // scalar range_flow

    float3* A = (float3*)d_ws;                                        // 30 MB
    float3* B = (float3*)((char*)d_ws + (size_t)48 * 1024 * 1024);    // 30 MB

    const dim3 blk(256);
    const dim3 grd(VOX_BLOCKS);                 // 10240 blocks

    // 7 dispatches, no repack: s1 reads planar velocity (x 2^-7 folded, exact)
    diffeo_step<true , false><<<grd, blk, 0, stream>>>(vel, rf, A);       // s1
    diffeo_step<false, false><<<grd, blk, 0, stream>>>(A,   rf, B);       // s2
    diffeo_step<false, false><<<grd, blk, 0, stream>>>(B,   rf, A);       // s3
    diffeo_step<false, false><<<grd, blk, 0, stream>>>(A,   rf, B);       // s4
    diffeo_step<false, false><<<grd, blk, 0, stream>>>(B,   rf, A);       // s5
    diffeo_step<false, false><<<grd, blk, 0, stream>>>(A,   rf, B);       // s6
    diffeo_step<false, true ><<<grd, blk, 0, stream>>>(B,   rf, d_out);   // s7
}